// Round 6
// baseline (24.320 us; speedup 1.0000x reference)
//
#include <hip/hip_runtime.h>

// Problem constants (match the reference file).
#define IN_F   4096
#define OUT_F  4094   // IN_FEATURES - 2
#define BATCH_ 4096
#define WCOLS  3      // min(3, OUT_F)

typedef float f32x4 __attribute__((ext_vector_type(4)));
typedef float f32x2 __attribute__((ext_vector_type(2)));

// ---------------------------------------------------------------------------
// One 256-thread block per row b, fully fused with INSTRUCTION-level r/w mix:
//   - same unrolled loop issues the row's input loads (+FMA vs 3 L2-resident
//     weight rows) AND the row's zero stores -> every wave keeps both a read
//     and a write stream in flight (stores don't depend on the loads).
//   - all writes to a row come from one block -> output lines single-owner,
//     no cross-XCD partial-line ping-pong.
//   - temporal accesses only: 128 MiB working set lives in the 256 MiB L3
//     across graph replays (nt hints cost +12 µs, R4 vs R5 A/B).
//
// Row byte base = b*4094*4 = b*16376; 16376 % 16 == 8, so:
//   even rows: scalar col3, f32x4 cols 4..4091 (1022), f32x2 cols 4092..4093
//   odd  rows: scalar col3, f32x2 cols 4..5, f32x4 cols 6..4093 (1022)
// Zeros cover cols 3..4093; cols 0..2 are written once after the reduction.
// ---------------------------------------------------------------------------
__global__ __launch_bounds__(256) void fused_row_kernel(const float* __restrict__ in,
                                                        const float* __restrict__ w,
                                                        const float* __restrict__ bias,
                                                        float* __restrict__ out) {
    const int b   = blockIdx.x;
    const int tid = threadIdx.x;

    const f32x4* __restrict__ row = (const f32x4*)(in + (long)b * IN_F);
    const f32x4* __restrict__ w0  = (const f32x4*)(w);
    const f32x4* __restrict__ w1  = (const f32x4*)(w + IN_F);
    const f32x4* __restrict__ w2  = (const f32x4*)(w + 2 * IN_F);

    float* __restrict__ base = out + (long)b * OUT_F;
    const int odd = b & 1;
    f32x4* __restrict__ zp = (f32x4*)(base + (odd ? 6 : 4));   // 16B-aligned

    const f32x4 z4 = {0.f, 0.f, 0.f, 0.f};
    const f32x2 z2 = {0.f, 0.f};
    if (tid == 0)  base[3] = 0.f;                              // scalar edge
    if (tid == 64) *(f32x2*)(base + (odd ? 4 : 4092)) = z2;    // f32x2 edge

    float s0 = 0.f, s1 = 0.f, s2 = 0.f;

    // 1024 f32x4 loads + 1022 f32x4 zero-stores, interleaved in one loop.
    #pragma unroll 4
    for (int i = tid; i < IN_F / 4; i += 256) {
        f32x4 x = row[i];
        f32x4 a = w0[i];
        f32x4 c = w1[i];
        f32x4 d = w2[i];
        if (i < 1022) zp[i] = z4;   // independent of loads -> issues alongside
        s0 = fmaf(x.x, a.x, fmaf(x.y, a.y, fmaf(x.z, a.z, fmaf(x.w, a.w, s0))));
        s1 = fmaf(x.x, c.x, fmaf(x.y, c.y, fmaf(x.z, c.z, fmaf(x.w, c.w, s1))));
        s2 = fmaf(x.x, d.x, fmaf(x.y, d.y, fmaf(x.z, d.z, fmaf(x.w, d.w, s2))));
    }

    // Wave-level reduction (wave = 64 lanes on gfx950).
    #pragma unroll
    for (int off = 32; off > 0; off >>= 1) {
        s0 += __shfl_down(s0, off);
        s1 += __shfl_down(s1, off);
        s2 += __shfl_down(s2, off);
    }

    __shared__ float red[4][WCOLS];
    const int wave = tid >> 6;
    const int lane = tid & 63;
    if (lane == 0) {
        red[wave][0] = s0;
        red[wave][1] = s1;
        red[wave][2] = s2;
    }
    __syncthreads();

    if (tid < WCOLS) {
        float t = red[0][tid] + red[1][tid] + red[2][tid] + red[3][tid];
        base[tid] = t + (float)IN_F * bias[tid];   // disjoint from zeroed cols
    }
}

extern "C" void kernel_launch(void* const* d_in, const int* in_sizes, int n_in,
                              void* d_out, int out_size, void* d_ws, size_t ws_size,
                              hipStream_t stream) {
    const float* in   = (const float*)d_in[0];   // (4096, 4096) fp32
    const float* w    = (const float*)d_in[1];   // (4094, 4096) fp32
    const float* bias = (const float*)d_in[2];   // (4094,) fp32
    float* out = (float*)d_out;                  // (4096, 4094) fp32

    fused_row_kernel<<<BATCH_, 256, 0, stream>>>(in, w, bias, out);
}